// Round 1
// baseline (107.779 us; speedup 1.0000x reference)
//
#include <hip/hip_runtime.h>
#include <math.h>

#define NA 5
#define NC 20
#define NH 38
#define NW 38
#define MAX_BOXES 50
#define SPAT (NH * NW)            // 1444
#define CELLS_PER_B (NA * SPAT)   // 7220
#define OBJECT_SCALE 5.0f
#define NOOBJECT_SCALE 1.0f

__constant__ float c_aw[NA] = {1.3221f, 3.19275f, 5.05587f, 9.47112f, 11.2364f};
__constant__ float c_ah[NA] = {1.73145f, 4.00944f, 8.09892f, 4.84053f, 10.0071f};

struct WinRec { int cell; float tx, ty, tw, th, iou, gcls; int pad; }; // 32 B

__device__ __forceinline__ float sigmoidf_(float v) { return 1.f / (1.f + expf(-v)); }

__device__ __forceinline__ float iou_cwh8(float x1, float y1, float w1, float h1,
                                          float x2, float y2, float w2, float h2) {
  float uw = fmaxf(x1 + w1 * 0.5f, x2 + w2 * 0.5f) - fminf(x1 - w1 * 0.5f, x2 - w2 * 0.5f);
  float uh = fmaxf(y1 + h1 * 0.5f, y2 + h2 * 0.5f) - fminf(y1 - h1 * 0.5f, y2 - h2 * 0.5f);
  float cw = w1 + w2 - uw;
  float ch = h1 + h2 - uh;
  float inter = (cw <= 0.f || ch <= 0.f) ? 0.f : cw * ch;
  return inter / (w1 * h1 + w2 * h2 - inter);
}

// One block per batch, one wave; lane t handles gt box t (<50).
__global__ __launch_bounds__(64) void prep_kernel(
    const float* __restrict__ out, const float* __restrict__ target,
    float* __restrict__ gtpre, WinRec* __restrict__ win) {
  int b = blockIdx.x;
  int t = threadIdx.x;
  float cls = 0.f, x = 0.f, y = 0.f, w = 0.f, h = 0.f;
  if (t < MAX_BOXES) {
    const float* tg = target + (size_t)(b * MAX_BOXES + t) * 5;
    cls = tg[0]; x = tg[1]; y = tg[2]; w = tg[3]; h = tg[4];
  }
  // valid = cumprod(x != 0) along t
  unsigned long long nz = __ballot(t < MAX_BOXES && x != 0.f);
  unsigned long long low = (t < 63) ? ((1ull << (t + 1)) - 1ull) : ~0ull;
  bool valid = (t < MAX_BOXES) && ((nz & low) == low);

  float gx = x * NW, gy = y * NH, gw = w * NW, gh = h * NH;

  // best anchor by IOU of (0,0,gw,gh) vs (0,0,aw,ah); first max wins (like argmax)
  int best = 0; float bestiou = -1.f;
#pragma unroll
  for (int a = 0; a < NA; ++a) {
    float aiou = iou_cwh8(0.f, 0.f, gw, gh, 0.f, 0.f, c_aw[a], c_ah[a]);
    if (aiou > bestiou) { bestiou = aiou; best = a; }
  }
  int gi = min(max((int)gx, 0), NW - 1);   // trunc == astype(int32) for positive
  int gj = min(max((int)gy, 0), NH - 1);

  // pred box at (b, best, gj, gi)
  const float* base = out + ((size_t)(b * NA + best) * 25) * SPAT + gj * NW + gi;
  float px = sigmoidf_(base[0]) + (float)gi;
  float py = sigmoidf_(base[SPAT]) + (float)gj;
  float pw = expf(base[2 * SPAT]) * c_aw[best];
  float ph = expf(base[3 * SPAT]) * c_ah[best];
  float iou_gt = iou_cwh8(gx, gy, gw, gh, px, py, pw, ph);

  int cell = best * SPAT + gj * NW + gi;
  unsigned long long vm = __ballot(valid);
  // last valid writer to a cell wins: t is winner iff valid and no valid t'>t shares cell
  bool winner = valid;
  for (int tp = 0; tp < MAX_BOXES; ++tp) {
    int c2 = __shfl(cell, tp);
    if (tp > t && ((vm >> tp) & 1ull) && c2 == cell) winner = false;
  }

  if (t < MAX_BOXES) {
    float* g = gtpre + (size_t)(b * MAX_BOXES + t) * 8;
    if (valid) {
      g[0] = gx - gw * 0.5f; g[1] = gx + gw * 0.5f;
      g[2] = gy - gh * 0.5f; g[3] = gy + gh * 0.5f;
      g[4] = gw; g[5] = gh; g[6] = 0.375f * (gw * gh); g[7] = 0.f;
    } else {
      // far-away sentinel: cw always < 0, never suppresses
      g[0] = 1e30f; g[1] = 1e30f; g[2] = 1e30f; g[3] = 1e30f;
      g[4] = 1.f; g[5] = 1.f; g[6] = 0.f; g[7] = 0.f;
    }
    WinRec wr;
    wr.cell = winner ? cell : -1;
    wr.tx = gx - (float)gi;
    wr.ty = gy - (float)gj;
    wr.tw = logf(gw / c_aw[best]);
    wr.th = logf(gh / c_ah[best]);
    wr.iou = iou_gt;
    wr.gcls = cls;
    wr.pad = 0;
    win[b * MAX_BOXES + t] = wr;
  }
}

// grid: (ceil(7220/256), nB); one thread per (anchor, j, i) cell
__global__ __launch_bounds__(256) void main_kernel(
    const float* __restrict__ out, const float* __restrict__ gtpre,
    const WinRec* __restrict__ win, float* __restrict__ partials) {
  int b = blockIdx.y;
  int s0 = blockIdx.x * 256;
  int s = s0 + threadIdx.x;

  __shared__ float4 sb_lo[MAX_BOXES];   // blx, bhx, bly, bhy
  __shared__ float4 sb_hi[MAX_BOXES];   // gw, gh, 0.375*area_g, pad
  __shared__ int s_wcnt;
  __shared__ int s_wcell[MAX_BOXES];
  __shared__ float s_wdata[MAX_BOXES][6];
  __shared__ float s_red[4];

  if (threadIdx.x == 0) s_wcnt = 0;
  __syncthreads();
  if (threadIdx.x < MAX_BOXES) {
    const float4* g = (const float4*)(gtpre + (size_t)(b * MAX_BOXES + threadIdx.x) * 8);
    sb_lo[threadIdx.x] = g[0];
    sb_hi[threadIdx.x] = g[1];
    WinRec wr = win[b * MAX_BOXES + threadIdx.x];
    if (wr.cell >= s0 && wr.cell < s0 + 256) {   // block-local winner filter
      int k = atomicAdd(&s_wcnt, 1);
      s_wcell[k] = wr.cell;
      s_wdata[k][0] = wr.tx; s_wdata[k][1] = wr.ty; s_wdata[k][2] = wr.tw;
      s_wdata[k][3] = wr.th; s_wdata[k][4] = wr.iou; s_wdata[k][5] = wr.gcls;
    }
  }
  __syncthreads();

  float acc = 0.f;
  if (s < CELLS_PER_B) {
    int a = s / SPAT;
    int r = s - a * SPAT;
    int i = r % NW;
    int j = r / NW;
    const float* base = out + ((size_t)(b * NA + a) * 25) * SPAT + r;
    float v0 = base[0];
    float v1 = base[SPAT];
    float v2 = base[2 * SPAT];
    float v3 = base[3 * SPAT];
    float v4 = base[4 * SPAT];
    float xs = sigmoidf_(v0), ys = sigmoidf_(v1), confs = sigmoidf_(v4);
    float pw = expf(v2) * c_aw[a], ph = expf(v3) * c_ah[a];
    float px = xs + (float)i, py = ys + (float)j;
    float plx = px - pw * 0.5f, phx = px + pw * 0.5f;
    float ply = py - ph * 0.5f, phy = py + ph * 0.5f;
    float ap375 = 0.375f * (pw * ph);

    // max_iou > 0.6  <=>  exists t: inter > 0.375*(area_p + area_g)   (no divide, no max)
    bool suppress = false;
#pragma unroll 10
    for (int t = 0; t < MAX_BOXES; ++t) {
      float4 lo = sb_lo[t];
      float4 hi = sb_hi[t];
      float uw = fmaxf(phx, lo.y) - fminf(plx, lo.x);
      float uh = fmaxf(phy, lo.w) - fminf(ply, lo.z);
      float cw = (pw + hi.x) - uw;
      float ch = (ph + hi.y) - uh;
      float inter = cw * ch;
      suppress = suppress | ((cw > 0.f) & (ch > 0.f) & (inter > (hi.z + ap375)));
    }
    float conf_mask = suppress ? 0.f : NOOBJECT_SCALE;
    float tx = 0.5f, ty = 0.5f, tw = 0.f, th = 0.f, tconf = 0.f;
    float clsloss = 0.f;
    int cnt = s_wcnt;
    for (int k = 0; k < cnt; ++k) {
      if (s_wcell[k] == s) {
        conf_mask = OBJECT_SCALE;
        tx = s_wdata[k][0]; ty = s_wdata[k][1];
        tw = s_wdata[k][2]; th = s_wdata[k][3];
        tconf = s_wdata[k][4];
        int label = (int)s_wdata[k][5];
        const float* cb = base + 5 * SPAT;
        float m = -1e30f, lv = 0.f;
        for (int c = 0; c < NC; ++c) {
          float v = cb[c * SPAT];
          if (c == label) lv = v;
          m = fmaxf(m, v);
        }
        float ssum = 0.f;
        for (int c = 0; c < NC; ++c) ssum += expf(cb[c * SPAT] - m);
        clsloss = (m + logf(ssum)) - lv;   // -log_softmax[label]
      }
    }
    float dx = xs - tx, dy = ys - ty, dw = v2 - tw, dh = v3 - th, dc = confs - tconf;
    acc = 0.5f * (dx * dx + dy * dy + dw * dw + dh * dh + conf_mask * (dc * dc)) + clsloss;
  }

  // block reduction: wave shuffle + LDS across 4 waves
  for (int o = 32; o > 0; o >>= 1) acc += __shfl_down(acc, o, 64);
  int wid = threadIdx.x >> 6, lane = threadIdx.x & 63;
  if (lane == 0) s_red[wid] = acc;
  __syncthreads();
  if (threadIdx.x == 0)
    partials[blockIdx.y * gridDim.x + blockIdx.x] = s_red[0] + s_red[1] + s_red[2] + s_red[3];
}

__global__ __launch_bounds__(256) void reduce_kernel(
    const float* __restrict__ partials, int n, float* __restrict__ outv) {
  float acc = 0.f;
  for (int i = threadIdx.x; i < n; i += 256) acc += partials[i];
  for (int o = 32; o > 0; o >>= 1) acc += __shfl_down(acc, o, 64);
  __shared__ float s_red[4];
  int wid = threadIdx.x >> 6, lane = threadIdx.x & 63;
  if (lane == 0) s_red[wid] = acc;
  __syncthreads();
  if (threadIdx.x == 0) outv[0] = s_red[0] + s_red[1] + s_red[2] + s_red[3];
}

extern "C" void kernel_launch(void* const* d_in, const int* in_sizes, int n_in,
                              void* d_out, int out_size, void* d_ws, size_t ws_size,
                              hipStream_t stream) {
  const float* out = (const float*)d_in[0];
  const float* target = (const float*)d_in[1];
  int nB = in_sizes[0] / (NA * (5 + NC) * SPAT);

  float* gtpre = (float*)d_ws;                                               // nB*50*8 floats
  WinRec* win = (WinRec*)((char*)d_ws + (size_t)nB * MAX_BOXES * 8 * sizeof(float));
  float* partials = (float*)((char*)win + (size_t)nB * MAX_BOXES * sizeof(WinRec));

  int gx = (CELLS_PER_B + 255) / 256;  // 29
  hipLaunchKernelGGL(prep_kernel, dim3(nB), dim3(64), 0, stream, out, target, gtpre, win);
  hipLaunchKernelGGL(main_kernel, dim3(gx, nB), dim3(256), 0, stream, out, gtpre, win, partials);
  hipLaunchKernelGGL(reduce_kernel, dim3(1), dim3(256), 0, stream, partials, gx * nB, (float*)d_out);
}